// Round 7
// baseline (478.135 us; speedup 1.0000x reference)
//
#include <hip/hip_runtime.h>
#include <cstdint>
#include <cstddef>

typedef unsigned short ushort_t;
typedef short    bf16x8 __attribute__((ext_vector_type(8)));   // MFMA A/B frag (4 VGPR)
typedef float    f32x4  __attribute__((ext_vector_type(4)));   // MFMA C/D frag
typedef uint4    __attribute__((may_alias)) uint4_a;
typedef ushort4  __attribute__((may_alias)) ushort4_a;
typedef float4   __attribute__((may_alias)) float4_a;
typedef float2   __attribute__((may_alias)) float2_a;
typedef unsigned __attribute__((may_alias)) uint_a;

constexpr int SEQ = 4096, HID = 2048, NHEADS = 16, NKVH = 4, HDIM = 128;
constexpr int QD  = NHEADS * HDIM;   // 2048
constexpr int KVD = NKVH * HDIM;     // 512
constexpr int KVL = 2 * KVD;         // 1024: interleaved k|v row stride
constexpr int NPART = 56;            // partial chunks per head (t=16..23:3, t=24..31:4)

static __device__ __forceinline__ float bf2f(ushort_t u) {
    return __uint_as_float(((unsigned)u) << 16);
}
static __device__ __forceinline__ ushort_t f2bf(float f) {
    unsigned x = __float_as_uint(f);
    unsigned r = x + 0x7FFFu + ((x >> 16) & 1u);   // RNE
    return (ushort_t)(r >> 16);
}
static __device__ __forceinline__ unsigned pack2(float lo, float hi) {
    return (unsigned)f2bf(lo) | ((unsigned)f2bf(hi) << 16);
}
// HW packed f32->bf16 (RNE), 1 instr instead of ~7 (T12 primitive; no builtin on gfx950)
static __device__ __forceinline__ unsigned cvt_pk(float lo, float hi) {
    unsigned r;
    asm("v_cvt_pk_bf16_f32 %0, %1, %2" : "=v"(r) : "v"(lo), "v"(hi));
    return r;
}

// async global->LDS, 16B per lane; LDS dest = wave-uniform base + lane*16
static __device__ __forceinline__ void gld16(const ushort_t* g, ushort_t* l) {
    __builtin_amdgcn_global_load_lds(
        (const __attribute__((address_space(1))) unsigned*)g,
        (__attribute__((address_space(3))) unsigned*)l, 16, 0, 0);
}

// ---------------------------------------------------------------------------
// X fp32 -> bf16 elementwise
// ---------------------------------------------------------------------------
__global__ __launch_bounds__(256) void cast_f32_bf16(
    const float* __restrict__ in, ushort_t* __restrict__ out, int n)
{
    int i = (blockIdx.x * 256 + threadIdx.x) * 8;
    if (i >= n) return;
    float4 a = *(const float4_a*)(in + i);
    float4 b = *(const float4_a*)(in + i + 4);
    uint4 o;
    o.x = pack2(a.x, a.y); o.y = pack2(a.z, a.w);
    o.z = pack2(b.x, b.y); o.w = pack2(b.z, b.w);
    *(uint4_a*)(out + i) = o;
}

// ---------------------------------------------------------------------------
// W[K,N] fp32 -> WT[N,K] bf16 (32x32 LDS-tiled transpose+cast)
// ---------------------------------------------------------------------------
__global__ __launch_bounds__(256) void transpose_cast(
    const float* __restrict__ W, ushort_t* __restrict__ WT, int K, int N)
{
    __shared__ float tl[32][36];
    const int k0 = blockIdx.x * 32, n0 = blockIdx.y * 32;
    const int t  = threadIdx.x;
    {
        int i = t >> 3, jb = (t & 7) * 4;
        *(float4_a*)&tl[i][jb] = *(const float4_a*)(W + (size_t)(k0 + i) * N + n0 + jb);
    }
    __syncthreads();
    {
        int n = t >> 3, kb = (t & 7) * 4;
        ushort4 o;
        o.x = f2bf(tl[kb + 0][n]); o.y = f2bf(tl[kb + 1][n]);
        o.z = f2bf(tl[kb + 2][n]); o.w = f2bf(tl[kb + 3][n]);
        *(ushort4_a*)(WT + (size_t)(n0 + n) * K + k0 + kb) = o;
    }
}

// ---------------------------------------------------------------------------
// m97-style MFMA GEMM: C = A[M,K] * Bt[N,K]^T, bf16 in, fp32 acc.
// 256 thr / 4 waves, tile 128x128, BK=32, global_load_lds(16B) into unpadded
// XOR-swizzled LDS (stored chunk = chunk ^ (row&3); chunk = 8 shorts).
// Epilogue routes cols < split -> C1 (ld1), else C2 (ld2). out_f32 -> C1 fp32.
// ---------------------------------------------------------------------------
__global__ __launch_bounds__(256) void gemm_mfma(
    const ushort_t* __restrict__ A, int lda,
    const ushort_t* __restrict__ Bt, int ldb,
    void* __restrict__ C1, int ld1, void* __restrict__ C2, int ld2,
    int split, int N, int K, int out_f32)
{
    __shared__ ushort_t as[128 * 32];   // 8 KB, unpadded (dma-contiguous)
    __shared__ ushort_t bs[128 * 32];

    const int t    = threadIdx.x;
    const int mb   = blockIdx.y * 128, nb = blockIdx.x * 128;
    const int w    = t >> 6, lane = t & 63, quad = lane >> 4, l15 = lane & 15;
    const int wm   = (w >> 1) * 64, wn = (w & 1) * 64;

    // dma maps: round r in {0,1}: rows (r*4+w)*16 + lane/4, chunk lane&3,
    // global chunk = (lane&3) ^ (row&3)
    const int dr_row = lane >> 2, dr_c = lane & 3;
    const int rA0 = w * 16 + dr_row, rA1 = 64 + w * 16 + dr_row;
    const ushort_t* a0p = A  + (size_t)(mb + rA0) * lda + (dr_c ^ (rA0 & 3)) * 8;
    const ushort_t* a1p = A  + (size_t)(mb + rA1) * lda + (dr_c ^ (rA1 & 3)) * 8;
    const ushort_t* b0p = Bt + (size_t)(nb + rA0) * ldb + (dr_c ^ (rA0 & 3)) * 8;
    const ushort_t* b1p = Bt + (size_t)(nb + rA1) * ldb + (dr_c ^ (rA1 & 3)) * 8;
    ushort_t* asb0 = &as[(w) * 512];        ushort_t* asb1 = &as[(4 + w) * 512];
    ushort_t* bsb0 = &bs[(w) * 512];        ushort_t* bsb1 = &bs[(4 + w) * 512];

    f32x4 acc[4][4];
#pragma unroll
    for (int i = 0; i < 4; i++)
#pragma unroll
        for (int j = 0; j < 4; j++) acc[i][j] = (f32x4)0.f;

    const int chunk = quad ^ (l15 & 3);   // swizzled frag chunk

    for (int kb = 0; kb < K; kb += 32) {
        __syncthreads();                   // prev iter's frag reads done
        gld16(a0p + kb, asb0);
        gld16(a1p + kb, asb1);
        gld16(b0p + kb, bsb0);
        gld16(b1p + kb, bsb1);
        __syncthreads();                   // compiler drains vmcnt before barrier

        bf16x8 af[4], bf[4];
#pragma unroll
        for (int mt = 0; mt < 4; mt++)
            af[mt] = *(const bf16x8*)&as[(wm + mt * 16 + l15) * 32 + chunk * 8];
#pragma unroll
        for (int nt = 0; nt < 4; nt++)
            bf[nt] = *(const bf16x8*)&bs[(wn + nt * 16 + l15) * 32 + chunk * 8];
#pragma unroll
        for (int mt = 0; mt < 4; mt++)
#pragma unroll
            for (int nt = 0; nt < 4; nt++)
                acc[mt][nt] = __builtin_amdgcn_mfma_f32_16x16x32_bf16(
                    af[mt], bf[nt], acc[mt][nt], 0, 0, 0);
    }

#pragma unroll
    for (int mt = 0; mt < 4; mt++)
#pragma unroll
        for (int nt = 0; nt < 4; nt++) {
            int colg = nb + wn + nt * 16 + l15;
#pragma unroll
            for (int r = 0; r < 4; r++) {
                int row = mb + wm + mt * 16 + quad * 4 + r;
                float v = acc[mt][nt][r];
                if (out_f32)            ((float*)C1)[(size_t)row * ld1 + colg] = v;
                else if (colg < split)  ((ushort_t*)C1)[(size_t)row * ld1 + colg] = f2bf(v);
                else                    ((ushort_t*)C2)[(size_t)row * ld2 + colg - split] = f2bf(v);
            }
        }
}

// ---------------------------------------------------------------------------
// RoPE in-place on bf16 [SEQ, ld] buffer, nh heads; precise sincosf.
// ---------------------------------------------------------------------------
__global__ __launch_bounds__(256) void rope_bf16(
    ushort_t* __restrict__ buf, int ld, int nh, const int* __restrict__ pos_ids)
{
    int idx  = blockIdx.x * 256 + threadIdx.x;
    int i    = idx & 63;
    int rem  = idx >> 6;
    int head = rem % nh;
    int s    = rem / nh;
    if (s >= SEQ) return;

    float pos = (float)pos_ids[s];
    float ang = pos * __expf(-(float)i * 0.14391156831212787f);
    float c, sn;
    sincosf(ang, &sn, &c);

    ushort_t* p = buf + (size_t)s * ld + head * HDIM;
    float x0 = bf2f(p[i]);
    float x1 = bf2f(p[i + 64]);
    p[i]      = f2bf(x0 * c - x1 * sn);
    p[i + 64] = f2bf(x1 * c + x0 * sn);
}

// ---------------------------------------------------------------------------
// Flash attention v10 (R14): split-K + 128-key SUPER-TILES. R13 hit 194us
// (occupancy 35%, 2 blocks/CU reg-capped) with ~49us/CU of per-iteration
// fixed cost (0.74us x 66 iters, measured R9<->R10 A/B). This round: stage
// 128 keys per barrier pair (one prefetch, two 64-key compute sub-steps with
// unchanged register footprint) -> 33 iters/CU, ~25us less fixed cost, and
// prefetch latency hides under 2x compute. LDS 70KB/block: 2 blocks/CU
// unchanged (140<=160KB; residency was reg-capped anyway). T5 setprio(1)
// around MFMA clusters (+4-7% proven on attn w/ independent blocks, m191).
// Slot map (64-key units, all ranges even -> clean super-tile pairing):
//   slot s<8:   single tiles t=15-s  (nkt 32..18), in-place O write
//   slot 8..63: chunk cs=s-8 of tiles t>=16 (t<24: 3 chunks, t>=24: 4),
//               writes unnormalized partials (m,l f32 + accO bf16) to d_out
//   slot >=64:  single tiles t=7-(s-64) (nkt 16..2), in-place
// combine_partials merges chunked tiles. S^T = K.Q^T, K/V register-prefetched
// into LDS, P transpose C->A in-register via ds_bpermute, exp2-domain
// softmax, defer-max (T13), cvt_pk (T12).
// ---------------------------------------------------------------------------
__global__ __launch_bounds__(512, 4) void flash_mfma(
    const ushort_t* Q, const ushort_t* __restrict__ KV,
    const int* __restrict__ amask, ushort_t* O,
    ushort_t* __restrict__ Opart, float2* __restrict__ ML)
{
    __shared__ ushort_t ks[128][136];    // K tile [key][dim], 272B rows, 34.0KB
    __shared__ ushort_t vt[128][136];    // V^T tile [dim][key 0..127], 34.0KB
    __shared__ float    bias[128];

    const int t = threadIdx.x, w = t >> 6, lane = t & 63;
    const int quad = lane >> 4, l15 = lane & 15;
    const int h = blockIdx.x, kvh = h >> 2;
    const int s = blockIdx.y;                        // slot 0..71
    const int kcol = kvh * HDIM, vcol = KVD + kvh * HDIM;
    const float scale2 = 0.08838834764831845f * 1.44269504088896340f; // /sqrt(128)*log2e

    // slot -> (tile, chunk range [64-key units], partial id)
    int tile, ktb, kte, pid;
    bool multi;
    if (s < 8)       { tile = 15 - s;        ktb = 0; kte = 2 * tile + 2; multi = false; pid = 0; }
    else if (s < 64) {
        int cs = s - 8;                               // 0..55
        int c;
        if (cs < 24) { tile = 16 + cs / 3; c = cs - (tile - 16) * 3; }
        else         { int d = cs - 24; tile = 24 + (d >> 2); c = d & 3; }
        int nkt = 2 * tile + 2;
        ktb = c * 16; kte = (ktb + 16 < nkt) ? ktb + 16 : nkt;
        multi = true; pid = h * NPART + cs;
    }
    else             { tile = 7 - (s - 64);  ktb = 0; kte = 2 * tile + 2; multi = false; pid = 0; }

    const int q0  = tile * 128;
    const int q0w = q0 + w * 16;

    // staging maps (512 threads, 128-key tile)
    const int krow = t >> 2,  kdo = (t & 3) * 32;    // K: 1 key row, 32 dims (64B)
    const int vkp  = t & 63,  vdg = t >> 6;          // V: keys 2vkp,2vkp+1, dims vdg*16..+16

    // bpermute indices for P transpose: quad' = 2*(quad&1) + (t4>>1)
    int bpi[4];
#pragma unroll
    for (int t4 = 0; t4 < 4; t4++)
        bpi[t4] = ((2 * (quad & 1) + (t4 >> 1)) * 16 + l15) * 4;
    const bool hi_half = (quad >> 1) != 0;           // selects mt' = 2kc+1

    // Q B-frags: qf[c] = Q[q0w + l15][c*32 + quad*8 ..+8]
    bf16x8 qf[4];
    {
        const ushort_t* qp = Q + (size_t)(q0w + l15) * QD + h * HDIM;
#pragma unroll
        for (int c = 0; c < 4; c++)
            qf[c] = *(const bf16x8*)(qp + c * 32 + quad * 8);
    }

    f32x4 accO[8];
#pragma unroll
    for (int j = 0; j < 8; j++) accO[j] = (f32x4)0.f;
    float m_s = -1e30f, l_s = 0.f;

    uint4 kst0, kst1, kst2, kst3, va0, va1, vb0, vb1;
    float bst = 0.f;
    auto stage_load = [&](int st) {                  // st in 128-key super-tiles
        const int k0 = st * 128;
        const ushort_t* kp = KV + (size_t)(k0 + krow) * KVL + kcol + kdo;
        kst0 = *(const uint4_a*)kp;
        kst1 = *(const uint4_a*)(kp + 8);
        kst2 = *(const uint4_a*)(kp + 16);
        kst3 = *(const uint4_a*)(kp + 24);
        const ushort_t* vp = KV + (size_t)(k0 + 2 * vkp) * KVL + vcol + vdg * 16;
        va0 = *(const uint4_a*)vp;
        va1 = *(const uint4_a*)(vp + 8);
        vb0 = *(const uint4_a*)(vp + KVL);
        vb1 = *(const uint4_a*)(vp + KVL + 8);
        if (t < 128) bst = amask[k0 + t] ? 0.f : -1e30f;
    };

    const int stb = ktb >> 1, ste = kte >> 1;        // ktb/kte always even
    stage_load(stb);

    for (int st = stb; st < ste; st++) {
        __syncthreads();   // prev super-tile fully consumed
        *(uint4_a*)&ks[krow][kdo]      = kst0;
        *(uint4_a*)&ks[krow][kdo + 8]  = kst1;
        *(uint4_a*)&ks[krow][kdo + 16] = kst2;
        *(uint4_a*)&ks[krow][kdo + 24] = kst3;
        {
            unsigned aw[4] = {va0.x, va0.y, va0.z, va0.w};
            unsigned bw[4] = {vb0.x, vb0.y, vb0.z, vb0.w};
#pragma unroll
            for (int i = 0; i < 4; i++) {
                *(uint_a*)&vt[vdg * 16 + 2 * i][2 * vkp] =
                    (aw[i] & 0xFFFFu) | (bw[i] << 16);
                *(uint_a*)&vt[vdg * 16 + 2 * i + 1][2 * vkp] =
                    (aw[i] >> 16) | (bw[i] & 0xFFFF0000u);
            }
            unsigned aw2[4] = {va1.x, va1.y, va1.z, va1.w};
            unsigned bw2[4] = {vb1.x, vb1.y, vb1.z, vb1.w};
#pragma unroll
            for (int i = 0; i < 4; i++) {
                *(uint_a*)&vt[vdg * 16 + 8 + 2 * i][2 * vkp] =
                    (aw2[i] & 0xFFFFu) | (bw2[i] << 16);
                *(uint_a*)&vt[vdg * 16 + 8 + 2 * i + 1][2 * vkp] =
                    (aw2[i] >> 16) | (bw2[i] & 0xFFFF0000u);
            }
        }
        if (t < 128) bias[t] = bst;
        __syncthreads();
        if (st + 1 < ste) stage_load(st + 1);   // 2 sub-steps of compute to land

#pragma unroll
        for (int ss = 0; ss < 2; ss++) {
            const int k0 = st * 128 + ss * 64;
            if (k0 > q0w + 15) continue;   // sub-tile fully masked for this wave
            const int kb = ss * 64;

            // ---- S^T = K Q^T ----
            f32x4 sx[4];
#pragma unroll
            for (int mt = 0; mt < 4; mt++) sx[mt] = (f32x4)0.f;
            __builtin_amdgcn_s_setprio(1);
#pragma unroll
            for (int c = 0; c < 4; c++)
#pragma unroll
                for (int mt = 0; mt < 4; mt++) {
                    bf16x8 kf = *(const bf16x8*)&ks[kb + mt * 16 + l15][c * 32 + quad * 8];
                    sx[mt] = __builtin_amdgcn_mfma_f32_16x16x32_bf16(kf, qf[c], sx[mt], 0, 0, 0);
                }
            __builtin_amdgcn_s_setprio(0);

            // ---- masked online softmax (exp2 domain); q-row = l15 ----
            const int qg = q0w + l15;
            const bool full = (k0 + 63 <= q0w);    // no causal masking needed
            float p[4][4];
            float mx = -1e30f;
#pragma unroll
            for (int mt = 0; mt < 4; mt++) {
                float4 b4 = *(const float4_a*)&bias[kb + mt * 16 + quad * 4];
                float br[4] = {b4.x, b4.y, b4.z, b4.w};
#pragma unroll
                for (int r = 0; r < 4; r++) {
                    float v = fmaf(sx[mt][r], scale2, br[r]);
                    if (!full) {
                        int kg = k0 + mt * 16 + quad * 4 + r;
                        v = (kg > qg) ? -1e30f : v;
                    }
                    p[mt][r] = v;
                    mx = fmaxf(mx, v);
                }
            }
            mx = fmaxf(mx, __shfl_xor(mx, 16));
            mx = fmaxf(mx, __shfl_xor(mx, 32));
            // defer-max (T13): keep old max unless it grew by >8 (exp2 domain)
            const bool renorm = !__all(mx <= m_s + 8.f);
            const float mnew = renorm ? fmaxf(m_s, mx) : m_s;
            float sum = 0.f;
            unsigned wlo[4], whi[4];
#pragma unroll
            for (int mt = 0; mt < 4; mt++) {
                float p0 = exp2f(p[mt][0] - mnew);
                float p1 = exp2f(p[mt][1] - mnew);
                float p2 = exp2f(p[mt][2] - mnew);
                float p3 = exp2f(p[mt][3] - mnew);
                sum += (p0 + p1) + (p2 + p3);
                wlo[mt] = cvt_pk(p0, p1);
                whi[mt] = cvt_pk(p2, p3);
            }
            sum += __shfl_xor(sum, 16);
            sum += __shfl_xor(sum, 32);

            if (renorm) {
                float alpha = exp2f(m_s - mnew);
                l_s *= alpha;
                // broadcast alpha lane-q -> register-q, rescale accO
                float a0 = __shfl(alpha, quad * 4 + 0);
                float a1 = __shfl(alpha, quad * 4 + 1);
                float a2 = __shfl(alpha, quad * 4 + 2);
                float a3 = __shfl(alpha, quad * 4 + 3);
#pragma unroll
                for (int j = 0; j < 8; j++) {
                    f32x4 a = accO[j];
                    a[0] *= a0; a[1] *= a1; a[2] *= a2; a[3] *= a3;
                    accO[j] = a;
                }
            }
            m_s = mnew;
            l_s += sum;

            // ---- P transpose C->A layout via ds_bpermute; then O += P V ----
#pragma unroll
            for (int kc = 0; kc < 2; kc++) {
                union { unsigned u[4]; bf16x8 v; } pf;
#pragma unroll
                for (int t4 = 0; t4 < 4; t4++) {
                    unsigned slo = (t4 & 1) ? whi[2 * kc]     : wlo[2 * kc];
                    unsigned shi = (t4 & 1) ? whi[2 * kc + 1] : wlo[2 * kc + 1];
                    int ra = __builtin_amdgcn_ds_bpermute(bpi[t4], (int)slo);
                    int rb = __builtin_amdgcn_ds_bpermute(bpi[t4], (int)shi);
                    pf.u[t4] = (unsigned)(hi_half ? rb : ra);
                }
                __builtin_amdgcn_s_setprio(1);
#pragma unroll
                for (int n8 = 0; n8 < 8; n8++) {
                    bf16x8 vf = *(const bf16x8*)&vt[n8 * 16 + l15][kb + kc * 32 + quad * 8];
                    accO[n8] = __builtin_amdgcn_mfma_f32_16x16x32_bf16(pf.v, vf, accO[n8], 0, 0, 0);
                }
                __builtin_amdgcn_s_setprio(0);
            }
        }
    }

    if (!multi) {
        // ---- epilogue: normalize rows, store bf16 in-place over Q region ----
        float linv = 1.0f / l_s;
#pragma unroll
        for (int r = 0; r < 4; r++) {
            float lr = __shfl(linv, quad * 4 + r);
            int row = q0w + quad * 4 + r;
            ushort_t* op = O + (size_t)row * QD + h * HDIM;
#pragma unroll
            for (int n8 = 0; n8 < 8; n8++)
                op[n8 * 16 + l15] = f2bf(accO[n8][r] * lr);
        }
    } else {
        // ---- partial epilogue: unnormalized accO (bf16) + per-row (m,l) ----
        ushort_t* op = Opart + (size_t)pid * (128 * 128);
#pragma unroll
        for (int r = 0; r < 4; r++) {
            int row = w * 16 + quad * 4 + r;
#pragma unroll
            for (int n8 = 0; n8 < 8; n8++)
                op[row * 128 + n8 * 16 + l15] = f2bf(accO[n8][r]);
        }
        if (quad == 0)
            ML[pid * 128 + w * 16 + l15] = make_float2(m_s, l_s);
    }
}

// ---------------------------------------------------------------------------
// Merge split-K partials for tiles t=16..31: O = (sum_c w_c accO_c)/(sum_c
// w_c l_c), w_c = 2^(m_c - M). 256 blocks (h, t), 256 thr: row = tid>>1,
// 64-dim half = (tid&1)*64.
// ---------------------------------------------------------------------------
__global__ __launch_bounds__(256) void combine_partials(
    const ushort_t* __restrict__ P, const float2* __restrict__ ML,
    ushort_t* __restrict__ O)
{
    const int h = blockIdx.x >> 4, tt = blockIdx.x & 15, tile = 16 + tt;
    const int nc = (tile < 24) ? 3 : 4;
    const int pid0 = h * NPART + ((tile < 24) ? tt * 3 : 24 + (tile - 24) * 4);
    const int tid = threadIdx.x;
    const int row = tid >> 1, dh = (tid & 1) << 6;

    float m_[4], l_[4];
    float M = -1e30f;
#pragma unroll
    for (int c = 0; c < 4; c++) {
        if (c < nc) {
            float2 v = *(const float2_a*)&ML[(pid0 + c) * 128 + row];
            m_[c] = v.x; l_[c] = v.y; M = fmaxf(M, v.x);
        } else { m_[c] = -1e30f; l_[c] = 0.f; }
    }
    float L = 0.f, wgt[4];
#pragma unroll
    for (int c = 0; c < 4; c++) { wgt[c] = exp2f(m_[c] - M); L += wgt[c] * l_[c]; }
    const float inv = 1.0f / L;

    ushort_t* op = O + (size_t)(tile * 128 + row) * QD + h * HDIM + dh;
    const size_t pbase = (size_t)row * 128 + dh;
#pragma unroll
    for (int g = 0; g < 8; g++) {            // 8 groups of 8 dims
        float acc[8] = {0.f, 0.f, 0.f, 0.f, 0.f, 0.f, 0.f, 0.f};
#pragma unroll
        for (int c = 0; c < 4; c++) {
            if (c < nc) {
                const ushort_t* pp = P + (size_t)(pid0 + c) * (128 * 128) + pbase + g * 8;
                uint4 v = *(const uint4_a*)pp;
                unsigned u[4] = {v.x, v.y, v.z, v.w};
#pragma unroll
                for (int j = 0; j < 4; j++) {
                    acc[2 * j]     += wgt[c] * bf2f((ushort_t)(u[j] & 0xFFFFu));
                    acc[2 * j + 1] += wgt[c] * bf2f((ushort_t)(u[j] >> 16));
                }
            }
        }
        uint4 o;
        o.x = pack2(acc[0] * inv, acc[1] * inv); o.y = pack2(acc[2] * inv, acc[3] * inv);
        o.z = pack2(acc[4] * inv, acc[5] * inv); o.w = pack2(acc[6] * inv, acc[7] * inv);
        *(uint4_a*)(op + g * 8) = o;
    }
}

// ---------------------------------------------------------------------------
// Memory plan: ws = qbuf/att 16MB | kvbuf (k|v interleaved) 8MB | (woT 8MB
// overwrites kvbuf after flash+combine). d_out scratch: wqkvT 12MB | xb 16MB
// until QKV GEMM; then flash partials: Opart 28MB | ML 0.9MB; O-GEMM output
// overwrites after combine.
// ---------------------------------------------------------------------------
extern "C" void kernel_launch(void* const* d_in, const int* in_sizes, int n_in,
                              void* d_out, int out_size, void* d_ws, size_t ws_size,
                              hipStream_t stream)
{
    const float* x     = (const float*)d_in[0];
    const int*   amask = (const int*)d_in[1];
    const int*   pos   = (const int*)d_in[2];
    const float* wq    = (const float*)d_in[3];
    const float* wk    = (const float*)d_in[4];
    const float* wv    = (const float*)d_in[5];
    const float* wo    = (const float*)d_in[6];
    float* out = (float*)d_out;

    ushort_t* wqkvT = (ushort_t*)d_out;                    // [3072][2048] bf16
    ushort_t* xb    = wqkvT + (size_t)3072 * HID;          // [4096][2048] bf16

    ushort_t* qbuf  = (ushort_t*)d_ws;                     // [4096][2048]
    ushort_t* kvbuf = qbuf + (size_t)SEQ * QD;             // [4096][1024] k|v
    ushort_t* woT   = kvbuf;                               // [2048][2048] after flash

    // split-K partials live in d_out during attention
    ushort_t* opart = (ushort_t*)d_out;                    // 896 x 128 x 128 bf16 = 28MB
    float2*   mlbuf = (float2*)((char*)d_out + (size_t)16 * NPART * 128 * 128 * 2);

    cast_f32_bf16<<<SEQ * HID / 8 / 256, 256, 0, stream>>>(x, xb, SEQ * HID);
    transpose_cast<<<dim3(HID / 32, QD / 32),  256, 0, stream>>>(wq, wqkvT, HID, QD);
    transpose_cast<<<dim3(HID / 32, KVD / 32), 256, 0, stream>>>(wk, wqkvT + (size_t)QD * HID, HID, KVD);
    transpose_cast<<<dim3(HID / 32, KVD / 32), 256, 0, stream>>>(wv, wqkvT + (size_t)(QD + KVD) * HID, HID, KVD);

    // fused QKV projection: cols [0,2048) -> qbuf, [2048,3072) -> kvbuf
    gemm_mfma<<<dim3(3072 / 128, SEQ / 128), 256, 0, stream>>>(
        xb, HID, wqkvT, HID, qbuf, QD, kvbuf, KVL, QD, 3072, HID, 0);

    rope_bf16<<<SEQ * NHEADS * 64 / 256, 256, 0, stream>>>(qbuf, QD, NHEADS, pos);
    rope_bf16<<<SEQ * NKVH  * 64 / 256, 256, 0, stream>>>(kvbuf, KVL, NKVH, pos);

    // split-K flash: 16 heads x 72 slots = 1152 blocks, 2 resident/CU + backfill
    flash_mfma<<<dim3(NHEADS, 72), 512, 0, stream>>>(
        qbuf, kvbuf, amask, qbuf, opart, mlbuf);
    combine_partials<<<dim3(256), 256, 0, stream>>>(opart, mlbuf, qbuf);

    transpose_cast<<<dim3(QD / 32, HID / 32), 256, 0, stream>>>(wo, woT, QD, HID);
    gemm_mfma<<<dim3(HID / 128, SEQ / 128), 256, 0, stream>>>(
        qbuf, QD, woT, QD, out, HID, out, HID, HID, HID, QD, 1);
}

// Round 8
// 449.246 us; speedup vs baseline: 1.0643x; 1.0643x over previous
//
#include <hip/hip_runtime.h>
#include <cstdint>
#include <cstddef>

typedef unsigned short ushort_t;
typedef short    bf16x8 __attribute__((ext_vector_type(8)));   // MFMA A/B frag (4 VGPR)
typedef float    f32x4  __attribute__((ext_vector_type(4)));   // MFMA C/D frag
typedef uint4    __attribute__((may_alias)) uint4_a;
typedef ushort4  __attribute__((may_alias)) ushort4_a;
typedef float4   __attribute__((may_alias)) float4_a;
typedef float2   __attribute__((may_alias)) float2_a;
typedef unsigned __attribute__((may_alias)) uint_a;

constexpr int SEQ = 4096, HID = 2048, NHEADS = 16, NKVH = 4, HDIM = 128;
constexpr int QD  = NHEADS * HDIM;   // 2048
constexpr int KVD = NKVH * HDIM;     // 512
constexpr int KVL = 2 * KVD;         // 1024: interleaved k|v row stride
constexpr int NPART = 56;            // partial chunks per head (t=16..23:3, t=24..31:4)

static __device__ __forceinline__ float bf2f(ushort_t u) {
    return __uint_as_float(((unsigned)u) << 16);
}
static __device__ __forceinline__ ushort_t f2bf(float f) {
    unsigned x = __float_as_uint(f);
    unsigned r = x + 0x7FFFu + ((x >> 16) & 1u);   // RNE
    return (ushort_t)(r >> 16);
}
static __device__ __forceinline__ unsigned pack2(float lo, float hi) {
    return (unsigned)f2bf(lo) | ((unsigned)f2bf(hi) << 16);
}
// HW packed f32->bf16 (RNE), 1 instr instead of ~7 (T12 primitive; no builtin on gfx950)
static __device__ __forceinline__ unsigned cvt_pk(float lo, float hi) {
    unsigned r;
    asm("v_cvt_pk_bf16_f32 %0, %1, %2" : "=v"(r) : "v"(lo), "v"(hi));
    return r;
}

// async global->LDS, 16B per lane; LDS dest = wave-uniform base + lane*16
static __device__ __forceinline__ void gld16(const ushort_t* g, ushort_t* l) {
    __builtin_amdgcn_global_load_lds(
        (const __attribute__((address_space(1))) unsigned*)g,
        (__attribute__((address_space(3))) unsigned*)l, 16, 0, 0);
}

// ---------------------------------------------------------------------------
// X fp32 -> bf16 elementwise
// ---------------------------------------------------------------------------
__global__ __launch_bounds__(256) void cast_f32_bf16(
    const float* __restrict__ in, ushort_t* __restrict__ out, int n)
{
    int i = (blockIdx.x * 256 + threadIdx.x) * 8;
    if (i >= n) return;
    float4 a = *(const float4_a*)(in + i);
    float4 b = *(const float4_a*)(in + i + 4);
    uint4 o;
    o.x = pack2(a.x, a.y); o.y = pack2(a.z, a.w);
    o.z = pack2(b.x, b.y); o.w = pack2(b.z, b.w);
    *(uint4_a*)(out + i) = o;
}

// ---------------------------------------------------------------------------
// W[K,N] fp32 -> WT[N,K] bf16 (32x32 LDS-tiled transpose+cast)
// ---------------------------------------------------------------------------
__global__ __launch_bounds__(256) void transpose_cast(
    const float* __restrict__ W, ushort_t* __restrict__ WT, int K, int N)
{
    __shared__ float tl[32][36];
    const int k0 = blockIdx.x * 32, n0 = blockIdx.y * 32;
    const int t  = threadIdx.x;
    {
        int i = t >> 3, jb = (t & 7) * 4;
        *(float4_a*)&tl[i][jb] = *(const float4_a*)(W + (size_t)(k0 + i) * N + n0 + jb);
    }
    __syncthreads();
    {
        int n = t >> 3, kb = (t & 7) * 4;
        ushort4 o;
        o.x = f2bf(tl[kb + 0][n]); o.y = f2bf(tl[kb + 1][n]);
        o.z = f2bf(tl[kb + 2][n]); o.w = f2bf(tl[kb + 3][n]);
        *(ushort4_a*)(WT + (size_t)(n0 + n) * K + k0 + kb) = o;
    }
}

// ---------------------------------------------------------------------------
// m97-style MFMA GEMM: C = A[M,K] * Bt[N,K]^T, bf16 in, fp32 acc.
// 256 thr / 4 waves, tile 128x128, BK=32, global_load_lds(16B) into unpadded
// XOR-swizzled LDS (stored chunk = chunk ^ (row&3); chunk = 8 shorts).
// Epilogue routes cols < split -> C1 (ld1), else C2 (ld2). out_f32 -> C1 fp32.
// ---------------------------------------------------------------------------
__global__ __launch_bounds__(256) void gemm_mfma(
    const ushort_t* __restrict__ A, int lda,
    const ushort_t* __restrict__ Bt, int ldb,
    void* __restrict__ C1, int ld1, void* __restrict__ C2, int ld2,
    int split, int N, int K, int out_f32)
{
    __shared__ ushort_t as[128 * 32];   // 8 KB, unpadded (dma-contiguous)
    __shared__ ushort_t bs[128 * 32];

    const int t    = threadIdx.x;
    const int mb   = blockIdx.y * 128, nb = blockIdx.x * 128;
    const int w    = t >> 6, lane = t & 63, quad = lane >> 4, l15 = lane & 15;
    const int wm   = (w >> 1) * 64, wn = (w & 1) * 64;

    // dma maps: round r in {0,1}: rows (r*4+w)*16 + lane/4, chunk lane&3,
    // global chunk = (lane&3) ^ (row&3)
    const int dr_row = lane >> 2, dr_c = lane & 3;
    const int rA0 = w * 16 + dr_row, rA1 = 64 + w * 16 + dr_row;
    const ushort_t* a0p = A  + (size_t)(mb + rA0) * lda + (dr_c ^ (rA0 & 3)) * 8;
    const ushort_t* a1p = A  + (size_t)(mb + rA1) * lda + (dr_c ^ (rA1 & 3)) * 8;
    const ushort_t* b0p = Bt + (size_t)(nb + rA0) * ldb + (dr_c ^ (rA0 & 3)) * 8;
    const ushort_t* b1p = Bt + (size_t)(nb + rA1) * ldb + (dr_c ^ (rA1 & 3)) * 8;
    ushort_t* asb0 = &as[(w) * 512];        ushort_t* asb1 = &as[(4 + w) * 512];
    ushort_t* bsb0 = &bs[(w) * 512];        ushort_t* bsb1 = &bs[(4 + w) * 512];

    f32x4 acc[4][4];
#pragma unroll
    for (int i = 0; i < 4; i++)
#pragma unroll
        for (int j = 0; j < 4; j++) acc[i][j] = (f32x4)0.f;

    const int chunk = quad ^ (l15 & 3);   // swizzled frag chunk

    for (int kb = 0; kb < K; kb += 32) {
        __syncthreads();                   // prev iter's frag reads done
        gld16(a0p + kb, asb0);
        gld16(a1p + kb, asb1);
        gld16(b0p + kb, bsb0);
        gld16(b1p + kb, bsb1);
        __syncthreads();                   // compiler drains vmcnt before barrier

        bf16x8 af[4], bf[4];
#pragma unroll
        for (int mt = 0; mt < 4; mt++)
            af[mt] = *(const bf16x8*)&as[(wm + mt * 16 + l15) * 32 + chunk * 8];
#pragma unroll
        for (int nt = 0; nt < 4; nt++)
            bf[nt] = *(const bf16x8*)&bs[(wn + nt * 16 + l15) * 32 + chunk * 8];
#pragma unroll
        for (int mt = 0; mt < 4; mt++)
#pragma unroll
            for (int nt = 0; nt < 4; nt++)
                acc[mt][nt] = __builtin_amdgcn_mfma_f32_16x16x32_bf16(
                    af[mt], bf[nt], acc[mt][nt], 0, 0, 0);
    }

#pragma unroll
    for (int mt = 0; mt < 4; mt++)
#pragma unroll
        for (int nt = 0; nt < 4; nt++) {
            int colg = nb + wn + nt * 16 + l15;
#pragma unroll
            for (int r = 0; r < 4; r++) {
                int row = mb + wm + mt * 16 + quad * 4 + r;
                float v = acc[mt][nt][r];
                if (out_f32)            ((float*)C1)[(size_t)row * ld1 + colg] = v;
                else if (colg < split)  ((ushort_t*)C1)[(size_t)row * ld1 + colg] = f2bf(v);
                else                    ((ushort_t*)C2)[(size_t)row * ld2 + colg - split] = f2bf(v);
            }
        }
}

// ---------------------------------------------------------------------------
// RoPE in-place on Q [SEQ,QD] and KV [SEQ,KVL] bf16 buffers in ONE launch
// (head-slot hs: 0..15 -> q heads, 16..19 -> kv heads). Precise sincosf.
// ---------------------------------------------------------------------------
__global__ __launch_bounds__(256) void rope_both(
    ushort_t* __restrict__ qb, ushort_t* __restrict__ kvb,
    const int* __restrict__ pos_ids)
{
    int idx  = blockIdx.x * 256 + threadIdx.x;
    int i    = idx & 63;
    int rem  = idx >> 6;
    int hs   = rem % (NHEADS + NKVH);
    int s    = rem / (NHEADS + NKVH);
    if (s >= SEQ) return;

    float pos = (float)pos_ids[s];
    float ang = pos * __expf(-(float)i * 0.14391156831212787f);
    float c, sn;
    sincosf(ang, &sn, &c);

    ushort_t* p = (hs < NHEADS)
        ? qb  + (size_t)s * QD  + hs * HDIM
        : kvb + (size_t)s * KVL + (hs - NHEADS) * HDIM;
    float x0 = bf2f(p[i]);
    float x1 = bf2f(p[i + 64]);
    p[i]      = f2bf(x0 * c - x1 * sn);
    p[i + 64] = f2bf(x1 * c + x0 * sn);
}

// ---------------------------------------------------------------------------
// Flash attention v11 (R15): exact R13 structure (best: 194us) + T5 setprio.
// R14's 128-key super-tiles regressed (194->208): per-iter cost tracks staged
// bytes in flight, not barrier count (FETCH 60->80MB, L2 behavior worse).
// Split-K slot map (R13, proven):
//   slot s<8:   single tiles t=15-s  (nkt 32..18), in-place O write
//   slot 8..63: chunk cs=s-8 of tiles t>=16 (t<24: 3 chunks, t>=24: 4),
//               writes unnormalized partials (m,l f32 + accO bf16) to d_out
//   slot >=64:  single tiles t=7-(s-64) (nkt 16..2), in-place
// Grid 16x72 = 1152 blocks, 2 resident/CU (reg-capped: 64 VGPR + 32 AGPR) +
// 640-block backfill queue; chains <= 32 units. 64-key tiles, S^T = K.Q^T,
// K/V register-prefetched into LDS, P transpose C->A via ds_bpermute,
// exp2-domain softmax, defer-max (T13), cvt_pk (T12). setprio(1) wraps MFMA
// clusters (T5: +4-7% attn with independent blocks/CU, m191).
// ---------------------------------------------------------------------------
__global__ __launch_bounds__(512, 4) void flash_mfma(
    const ushort_t* Q, const ushort_t* __restrict__ KV,
    const int* __restrict__ amask, ushort_t* O,
    ushort_t* __restrict__ Opart, float2* __restrict__ ML)
{
    __shared__ ushort_t ks[64][136];     // K tile [key][dim], 272B rows
    __shared__ ushort_t vt[128][72];     // V^T tile [dim][key], 144B rows
    __shared__ float    bias[64];

    const int t = threadIdx.x, w = t >> 6, lane = t & 63;
    const int quad = lane >> 4, l15 = lane & 15;
    const int h = blockIdx.x, kvh = h >> 2;
    const int s = blockIdx.y;                        // slot 0..71
    const int kcol = kvh * HDIM, vcol = KVD + kvh * HDIM;
    const float scale2 = 0.08838834764831845f * 1.44269504088896340f; // /sqrt(128)*log2e

    // slot -> (tile, chunk range, partial id)
    int tile, ktb, kte, pid;
    bool multi;
    if (s < 8)       { tile = 15 - s;        ktb = 0; kte = 2 * tile + 2; multi = false; pid = 0; }
    else if (s < 64) {
        int cs = s - 8;                               // 0..55
        int c;
        if (cs < 24) { tile = 16 + cs / 3; c = cs - (tile - 16) * 3; }
        else         { int d = cs - 24; tile = 24 + (d >> 2); c = d & 3; }
        int nkt = 2 * tile + 2;
        ktb = c * 16; kte = (ktb + 16 < nkt) ? ktb + 16 : nkt;
        multi = true; pid = h * NPART + cs;
    }
    else             { tile = 7 - (s - 64);  ktb = 0; kte = 2 * tile + 2; multi = false; pid = 0; }

    const int q0  = tile * 128;
    const int q0w = q0 + w * 16;

    // staging maps (512 threads)
    const int krow = t >> 3,  kdo = (t & 7) * 16;    // K: 1 key row, 16 dims
    const int vkp  = t & 31,  vdg = t >> 5;          // V: keys 2vkp,2vkp+1, dims vdg*8..+8

    // bpermute indices for P transpose: quad' = 2*(quad&1) + (t4>>1)
    int bpi[4];
#pragma unroll
    for (int t4 = 0; t4 < 4; t4++)
        bpi[t4] = ((2 * (quad & 1) + (t4 >> 1)) * 16 + l15) * 4;
    const bool hi_half = (quad >> 1) != 0;           // selects mt' = 2kc+1

    // Q B-frags: qf[c] = Q[q0w + l15][c*32 + quad*8 ..+8]
    bf16x8 qf[4];
    {
        const ushort_t* qp = Q + (size_t)(q0w + l15) * QD + h * HDIM;
#pragma unroll
        for (int c = 0; c < 4; c++)
            qf[c] = *(const bf16x8*)(qp + c * 32 + quad * 8);
    }

    f32x4 accO[8];
#pragma unroll
    for (int j = 0; j < 8; j++) accO[j] = (f32x4)0.f;
    float m_s = -1e30f, l_s = 0.f;

    uint4 kst[2], va, vb;
    float bst = 0.f;
    auto stage_load = [&](int kt) {
        const int k0 = kt * 64;
        const ushort_t* kp = KV + (size_t)(k0 + krow) * KVL + kcol + kdo;
        kst[0] = *(const uint4_a*)kp;
        kst[1] = *(const uint4_a*)(kp + 8);
        const ushort_t* vp = KV + (size_t)(k0 + 2 * vkp) * KVL + vcol + vdg * 8;
        va = *(const uint4_a*)vp;
        vb = *(const uint4_a*)(vp + KVL);
        if (t < 64) bst = amask[k0 + t] ? 0.f : -1e30f;
    };

    stage_load(ktb);

    for (int kt = ktb; kt < kte; kt++) {
        const int k0 = kt * 64;
        __syncthreads();   // prev tile fully consumed
        *(uint4_a*)&ks[krow][kdo]     = kst[0];
        *(uint4_a*)&ks[krow][kdo + 8] = kst[1];
        {
            unsigned aw[4] = {va.x, va.y, va.z, va.w};
            unsigned bw[4] = {vb.x, vb.y, vb.z, vb.w};
#pragma unroll
            for (int i = 0; i < 4; i++) {
                *(uint_a*)&vt[vdg * 8 + 2 * i][2 * vkp] =
                    (aw[i] & 0xFFFFu) | (bw[i] << 16);
                *(uint_a*)&vt[vdg * 8 + 2 * i + 1][2 * vkp] =
                    (aw[i] >> 16) | (bw[i] & 0xFFFF0000u);
            }
        }
        if (t < 64) bias[t] = bst;
        __syncthreads();
        if (kt + 1 < kte) stage_load(kt + 1);   // full compute window to land

        if (k0 > q0w + 15) continue;   // tile fully masked for this wave

        // ---- S^T = K Q^T ----
        f32x4 sx[4];
#pragma unroll
        for (int mt = 0; mt < 4; mt++) sx[mt] = (f32x4)0.f;
        __builtin_amdgcn_s_setprio(1);
#pragma unroll
        for (int c = 0; c < 4; c++)
#pragma unroll
            for (int mt = 0; mt < 4; mt++) {
                bf16x8 kf = *(const bf16x8*)&ks[mt * 16 + l15][c * 32 + quad * 8];
                sx[mt] = __builtin_amdgcn_mfma_f32_16x16x32_bf16(kf, qf[c], sx[mt], 0, 0, 0);
            }
        __builtin_amdgcn_s_setprio(0);

        // ---- masked online softmax (exp2 domain); q-row = l15, keys in regs ----
        const int qg = q0w + l15;
        const bool full = (k0 + 63 <= q0w);    // no causal masking needed
        float p[4][4];
        float mx = -1e30f;
#pragma unroll
        for (int mt = 0; mt < 4; mt++) {
            float4 b4 = *(const float4_a*)&bias[mt * 16 + quad * 4];
            float br[4] = {b4.x, b4.y, b4.z, b4.w};
#pragma unroll
            for (int r = 0; r < 4; r++) {
                float v = fmaf(sx[mt][r], scale2, br[r]);
                if (!full) {
                    int kg = k0 + mt * 16 + quad * 4 + r;
                    v = (kg > qg) ? -1e30f : v;
                }
                p[mt][r] = v;
                mx = fmaxf(mx, v);
            }
        }
        mx = fmaxf(mx, __shfl_xor(mx, 16));
        mx = fmaxf(mx, __shfl_xor(mx, 32));
        // defer-max (T13): keep old max unless it grew by >8 (exp2 domain,
        // P bounded by 2^8; bf16 pack + f32 accum tolerate)
        const bool renorm = !__all(mx <= m_s + 8.f);
        const float mnew = renorm ? fmaxf(m_s, mx) : m_s;
        float sum = 0.f;
        unsigned wlo[4], whi[4];
#pragma unroll
        for (int mt = 0; mt < 4; mt++) {
            float p0 = exp2f(p[mt][0] - mnew);
            float p1 = exp2f(p[mt][1] - mnew);
            float p2 = exp2f(p[mt][2] - mnew);
            float p3 = exp2f(p[mt][3] - mnew);
            sum += (p0 + p1) + (p2 + p3);
            wlo[mt] = cvt_pk(p0, p1);
            whi[mt] = cvt_pk(p2, p3);
        }
        sum += __shfl_xor(sum, 16);
        sum += __shfl_xor(sum, 32);

        if (renorm) {
            float alpha = exp2f(m_s - mnew);
            l_s *= alpha;
            // broadcast alpha lane-q -> register-q, rescale accO
            float a0 = __shfl(alpha, quad * 4 + 0);
            float a1 = __shfl(alpha, quad * 4 + 1);
            float a2 = __shfl(alpha, quad * 4 + 2);
            float a3 = __shfl(alpha, quad * 4 + 3);
#pragma unroll
            for (int j = 0; j < 8; j++) {
                f32x4 a = accO[j];
                a[0] *= a0; a[1] *= a1; a[2] *= a2; a[3] *= a3;
                accO[j] = a;
            }
        }
        m_s = mnew;
        l_s += sum;

        // ---- P transpose C->A layout via ds_bpermute; then O += P V ----
#pragma unroll
        for (int kc = 0; kc < 2; kc++) {
            union { unsigned u[4]; bf16x8 v; } pf;
#pragma unroll
            for (int t4 = 0; t4 < 4; t4++) {
                unsigned slo = (t4 & 1) ? whi[2 * kc]     : wlo[2 * kc];
                unsigned shi = (t4 & 1) ? whi[2 * kc + 1] : wlo[2 * kc + 1];
                int ra = __builtin_amdgcn_ds_bpermute(bpi[t4], (int)slo);
                int rb = __builtin_amdgcn_ds_bpermute(bpi[t4], (int)shi);
                pf.u[t4] = (unsigned)(hi_half ? rb : ra);
            }
            __builtin_amdgcn_s_setprio(1);
#pragma unroll
            for (int n8 = 0; n8 < 8; n8++) {
                bf16x8 vf = *(const bf16x8*)&vt[n8 * 16 + l15][kc * 32 + quad * 8];
                accO[n8] = __builtin_amdgcn_mfma_f32_16x16x32_bf16(pf.v, vf, accO[n8], 0, 0, 0);
            }
            __builtin_amdgcn_s_setprio(0);
        }
    }

    if (!multi) {
        // ---- epilogue: normalize rows, store bf16 in-place over Q region ----
        float linv = 1.0f / l_s;
#pragma unroll
        for (int r = 0; r < 4; r++) {
            float lr = __shfl(linv, quad * 4 + r);
            int row = q0w + quad * 4 + r;
            ushort_t* op = O + (size_t)row * QD + h * HDIM;
#pragma unroll
            for (int n8 = 0; n8 < 8; n8++)
                op[n8 * 16 + l15] = f2bf(accO[n8][r] * lr);
        }
    } else {
        // ---- partial epilogue: unnormalized accO (bf16) + per-row (m,l) ----
        ushort_t* op = Opart + (size_t)pid * (128 * 128);
#pragma unroll
        for (int r = 0; r < 4; r++) {
            int row = w * 16 + quad * 4 + r;
#pragma unroll
            for (int n8 = 0; n8 < 8; n8++)
                op[row * 128 + n8 * 16 + l15] = f2bf(accO[n8][r]);
        }
        if (quad == 0)
            ML[pid * 128 + w * 16 + l15] = make_float2(m_s, l_s);
    }
}

// ---------------------------------------------------------------------------
// Merge split-K partials for tiles t=16..31 (coalesced v2): per-row weights
// wc[c][row] = 2^(m_c - M)/L precomputed in LDS; main loop maps 8 lanes to
// one row's 128B contiguous span (read AND write dense; v1 was 16B reads at
// 256B stride). 256 blocks (h, t), 256 thr, 4 passes of 32 rows.
// ---------------------------------------------------------------------------
__global__ __launch_bounds__(256) void combine_partials(
    const ushort_t* __restrict__ P, const float2* __restrict__ ML,
    ushort_t* __restrict__ O)
{
    __shared__ float wc[4][128];
    const int h = blockIdx.x >> 4, tt = blockIdx.x & 15, tile = 16 + tt;
    const int nc = (tile < 24) ? 3 : 4;
    const int pid0 = h * NPART + ((tile < 24) ? tt * 3 : 24 + (tile - 24) * 4);
    const int tid = threadIdx.x;

    if (tid < 128) {
        const int row = tid;
        float m_[4], l_[4];
        float M = -1e30f;
#pragma unroll
        for (int c = 0; c < 4; c++) {
            if (c < nc) {
                float2 v = *(const float2_a*)&ML[(pid0 + c) * 128 + row];
                m_[c] = v.x; l_[c] = v.y; M = fmaxf(M, v.x);
            } else { m_[c] = -1e30f; l_[c] = 0.f; }
        }
        float L = 0.f, wgt[4];
#pragma unroll
        for (int c = 0; c < 4; c++) { wgt[c] = exp2f(m_[c] - M); L += wgt[c] * l_[c]; }
        const float inv = 1.0f / L;
#pragma unroll
        for (int c = 0; c < 4; c++) wc[c][row] = (c < nc) ? wgt[c] * inv : 0.f;
    }
    __syncthreads();

#pragma unroll
    for (int p = 0; p < 4; p++) {
        const int idx = p * 256 + tid;
        const int row = idx >> 3, seg = idx & 7;     // 16 cols per seg
        const size_t pb = (size_t)row * 128 + seg * 16;
        float acc[16];
#pragma unroll
        for (int j = 0; j < 16; j++) acc[j] = 0.f;
#pragma unroll
        for (int c = 0; c < 4; c++) {
            if (c < nc) {
                const ushort_t* pp = P + (size_t)(pid0 + c) * (128 * 128) + pb;
                uint4 v0 = *(const uint4_a*)pp;
                uint4 v1 = *(const uint4_a*)(pp + 8);
                const float wv_ = wc[c][row];
                unsigned u[8] = {v0.x, v0.y, v0.z, v0.w, v1.x, v1.y, v1.z, v1.w};
#pragma unroll
                for (int j = 0; j < 8; j++) {
                    acc[2 * j]     += wv_ * bf2f((ushort_t)(u[j] & 0xFFFFu));
                    acc[2 * j + 1] += wv_ * bf2f((ushort_t)(u[j] >> 16));
                }
            }
        }
        ushort_t* op = O + (size_t)(tile * 128 + row) * QD + h * HDIM + seg * 16;
        uint4 o0, o1;
        o0.x = pack2(acc[0],  acc[1]);  o0.y = pack2(acc[2],  acc[3]);
        o0.z = pack2(acc[4],  acc[5]);  o0.w = pack2(acc[6],  acc[7]);
        o1.x = pack2(acc[8],  acc[9]);  o1.y = pack2(acc[10], acc[11]);
        o1.z = pack2(acc[12], acc[13]); o1.w = pack2(acc[14], acc[15]);
        *(uint4_a*)op       = o0;
        *(uint4_a*)(op + 8) = o1;
    }
}

// ---------------------------------------------------------------------------
// Memory plan: ws = qbuf/att 16MB | kvbuf (k|v interleaved) 8MB | (woT 8MB
// overwrites kvbuf after flash+combine). d_out scratch: wqkvT 12MB | xb 16MB
// until QKV GEMM; then flash partials: Opart 28MB | ML 0.9MB; O-GEMM output
// overwrites after combine.
// ---------------------------------------------------------------------------
extern "C" void kernel_launch(void* const* d_in, const int* in_sizes, int n_in,
                              void* d_out, int out_size, void* d_ws, size_t ws_size,
                              hipStream_t stream)
{
    const float* x     = (const float*)d_in[0];
    const int*   amask = (const int*)d_in[1];
    const int*   pos   = (const int*)d_in[2];
    const float* wq    = (const float*)d_in[3];
    const float* wk    = (const float*)d_in[4];
    const float* wv    = (const float*)d_in[5];
    const float* wo    = (const float*)d_in[6];
    float* out = (float*)d_out;

    ushort_t* wqkvT = (ushort_t*)d_out;                    // [3072][2048] bf16
    ushort_t* xb    = wqkvT + (size_t)3072 * HID;          // [4096][2048] bf16

    ushort_t* qbuf  = (ushort_t*)d_ws;                     // [4096][2048]
    ushort_t* kvbuf = qbuf + (size_t)SEQ * QD;             // [4096][1024] k|v
    ushort_t* woT   = kvbuf;                               // [2048][2048] after flash

    // split-K partials live in d_out during attention
    ushort_t* opart = (ushort_t*)d_out;                    // 896 x 128 x 128 bf16 = 28MB
    float2*   mlbuf = (float2*)((char*)d_out + (size_t)16 * NPART * 128 * 128 * 2);

    cast_f32_bf16<<<SEQ * HID / 8 / 256, 256, 0, stream>>>(x, xb, SEQ * HID);
    transpose_cast<<<dim3(HID / 32, QD / 32),  256, 0, stream>>>(wq, wqkvT, HID, QD);
    transpose_cast<<<dim3(HID / 32, KVD / 32), 256, 0, stream>>>(wk, wqkvT + (size_t)QD * HID, HID, KVD);
    transpose_cast<<<dim3(HID / 32, KVD / 32), 256, 0, stream>>>(wv, wqkvT + (size_t)(QD + KVD) * HID, HID, KVD);

    // fused QKV projection: cols [0,2048) -> qbuf, [2048,3072) -> kvbuf
    gemm_mfma<<<dim3(3072 / 128, SEQ / 128), 256, 0, stream>>>(
        xb, HID, wqkvT, HID, qbuf, QD, kvbuf, KVL, QD, 3072, HID, 0);

    // fused RoPE on Q and KV in one launch
    rope_both<<<SEQ * (NHEADS + NKVH) * 64 / 256, 256, 0, stream>>>(qbuf, kvbuf, pos);

    // split-K flash: 16 heads x 72 slots = 1152 blocks, 2 resident/CU + backfill
    flash_mfma<<<dim3(NHEADS, 72), 512, 0, stream>>>(
        qbuf, kvbuf, amask, qbuf, opart, mlbuf);
    combine_partials<<<dim3(256), 256, 0, stream>>>(opart, mlbuf, qbuf);

    transpose_cast<<<dim3(QD / 32, HID / 32), 256, 0, stream>>>(wo, woT, QD, HID);
    gemm_mfma<<<dim3(HID / 128, SEQ / 128), 256, 0, stream>>>(
        qbuf, QD, woT, QD, out, HID, out, HID, HID, HID, QD, 1);
}

// Round 10
// 424.580 us; speedup vs baseline: 1.1261x; 1.0581x over previous
//
#include <hip/hip_runtime.h>
#include <cstdint>
#include <cstddef>

typedef unsigned short ushort_t;
typedef short    bf16x8 __attribute__((ext_vector_type(8)));   // MFMA A/B frag (4 VGPR)
typedef float    f32x4  __attribute__((ext_vector_type(4)));   // MFMA C/D frag
typedef uint4    __attribute__((may_alias)) uint4_a;
typedef ushort4  __attribute__((may_alias)) ushort4_a;
typedef float4   __attribute__((may_alias)) float4_a;
typedef float2   __attribute__((may_alias)) float2_a;
typedef unsigned __attribute__((may_alias)) uint_a;

constexpr int SEQ = 4096, HID = 2048, NHEADS = 16, NKVH = 4, HDIM = 128;
constexpr int QD  = NHEADS * HDIM;   // 2048
constexpr int KVD = NKVH * HDIM;     // 512
constexpr int KVL = 2 * KVD;         // 1024: interleaved k|v row stride
constexpr int NPART = 56;            // partial chunks per head (t=16..23:3, t=24..31:4)

static __device__ __forceinline__ float bf2f(ushort_t u) {
    return __uint_as_float(((unsigned)u) << 16);
}
static __device__ __forceinline__ ushort_t f2bf(float f) {
    unsigned x = __float_as_uint(f);
    unsigned r = x + 0x7FFFu + ((x >> 16) & 1u);   // RNE
    return (ushort_t)(r >> 16);
}
static __device__ __forceinline__ unsigned pack2(float lo, float hi) {
    return (unsigned)f2bf(lo) | ((unsigned)f2bf(hi) << 16);
}
// HW packed f32->bf16 (RNE), 1 instr instead of ~7 (T12 primitive; no builtin on gfx950)
static __device__ __forceinline__ unsigned cvt_pk(float lo, float hi) {
    unsigned r;
    asm("v_cvt_pk_bf16_f32 %0, %1, %2" : "=v"(r) : "v"(lo), "v"(hi));
    return r;
}

// async global->LDS, 16B per lane; LDS dest = wave-uniform base + lane*16
static __device__ __forceinline__ void gld16(const ushort_t* g, ushort_t* l) {
    __builtin_amdgcn_global_load_lds(
        (const __attribute__((address_space(1))) unsigned*)g,
        (__attribute__((address_space(3))) unsigned*)l, 16, 0, 0);
}

// ---------------------------------------------------------------------------
// X fp32 -> bf16 elementwise
// ---------------------------------------------------------------------------
__global__ __launch_bounds__(256) void cast_f32_bf16(
    const float* __restrict__ in, ushort_t* __restrict__ out, int n)
{
    int i = (blockIdx.x * 256 + threadIdx.x) * 8;
    if (i >= n) return;
    float4 a = *(const float4_a*)(in + i);
    float4 b = *(const float4_a*)(in + i + 4);
    uint4 o;
    o.x = pack2(a.x, a.y); o.y = pack2(a.z, a.w);
    o.z = pack2(b.x, b.y); o.w = pack2(b.z, b.w);
    *(uint4_a*)(out + i) = o;
}

// ---------------------------------------------------------------------------
// W[K,N] fp32 -> WT[N,K] bf16 (32x32 LDS-tiled transpose+cast)
// ---------------------------------------------------------------------------
__global__ __launch_bounds__(256) void transpose_cast(
    const float* __restrict__ W, ushort_t* __restrict__ WT, int K, int N)
{
    __shared__ float tl[32][36];
    const int k0 = blockIdx.x * 32, n0 = blockIdx.y * 32;
    const int t  = threadIdx.x;
    {
        int i = t >> 3, jb = (t & 7) * 4;
        *(float4_a*)&tl[i][jb] = *(const float4_a*)(W + (size_t)(k0 + i) * N + n0 + jb);
    }
    __syncthreads();
    {
        int n = t >> 3, kb = (t & 7) * 4;
        ushort4 o;
        o.x = f2bf(tl[kb + 0][n]); o.y = f2bf(tl[kb + 1][n]);
        o.z = f2bf(tl[kb + 2][n]); o.w = f2bf(tl[kb + 3][n]);
        *(ushort4_a*)(WT + (size_t)(n0 + n) * K + k0 + kb) = o;
    }
}

// ---------------------------------------------------------------------------
// Fused wq|wk|wv transpose+cast -> wqkvT rows [0,2048)|[2048,2560)|[2560,3072)
// (one launch instead of three; row-range selects source).
// ---------------------------------------------------------------------------
__global__ __launch_bounds__(256) void transpose_cast_qkv(
    const float* __restrict__ wq, const float* __restrict__ wk,
    const float* __restrict__ wv, ushort_t* __restrict__ WT)
{
    __shared__ float tl[32][36];
    const int k0 = blockIdx.x * 32, nb = blockIdx.y * 32;
    const int t  = threadIdx.x;
    const float* W; int n0, N;
    if (nb < 2048)      { W = wq; n0 = nb;        N = QD;  }
    else if (nb < 2560) { W = wk; n0 = nb - 2048; N = KVD; }
    else                { W = wv; n0 = nb - 2560; N = KVD; }
    {
        int i = t >> 3, jb = (t & 7) * 4;
        *(float4_a*)&tl[i][jb] = *(const float4_a*)(W + (size_t)(k0 + i) * N + n0 + jb);
    }
    __syncthreads();
    {
        int n = t >> 3, kb = (t & 7) * 4;
        ushort4 o;
        o.x = f2bf(tl[kb + 0][n]); o.y = f2bf(tl[kb + 1][n]);
        o.z = f2bf(tl[kb + 2][n]); o.w = f2bf(tl[kb + 3][n]);
        *(ushort4_a*)(WT + (size_t)(nb + n) * HID + k0 + kb) = o;
    }
}

// ---------------------------------------------------------------------------
// m97-style MFMA GEMM: C = A[M,K] * Bt[N,K]^T, bf16 in, fp32 acc.
// 256 thr / 4 waves, tile 128x128, BK=32, global_load_lds(16B) into unpadded
// XOR-swizzled LDS (stored chunk = chunk ^ (row&3); chunk = 8 shorts).
// Epilogue routes cols < split -> C1 (ld1), else C2 (ld2). out_f32 -> C1 fp32.
// ---------------------------------------------------------------------------
__global__ __launch_bounds__(256) void gemm_mfma(
    const ushort_t* __restrict__ A, int lda,
    const ushort_t* __restrict__ Bt, int ldb,
    void* __restrict__ C1, int ld1, void* __restrict__ C2, int ld2,
    int split, int N, int K, int out_f32)
{
    __shared__ ushort_t as[128 * 32];   // 8 KB, unpadded (dma-contiguous)
    __shared__ ushort_t bs[128 * 32];

    const int t    = threadIdx.x;
    const int mb   = blockIdx.y * 128, nb = blockIdx.x * 128;
    const int w    = t >> 6, lane = t & 63, quad = lane >> 4, l15 = lane & 15;
    const int wm   = (w >> 1) * 64, wn = (w & 1) * 64;

    // dma maps: round r in {0,1}: rows (r*4+w)*16 + lane/4, chunk lane&3,
    // global chunk = (lane&3) ^ (row&3)
    const int dr_row = lane >> 2, dr_c = lane & 3;
    const int rA0 = w * 16 + dr_row, rA1 = 64 + w * 16 + dr_row;
    const ushort_t* a0p = A  + (size_t)(mb + rA0) * lda + (dr_c ^ (rA0 & 3)) * 8;
    const ushort_t* a1p = A  + (size_t)(mb + rA1) * lda + (dr_c ^ (rA1 & 3)) * 8;
    const ushort_t* b0p = Bt + (size_t)(nb + rA0) * ldb + (dr_c ^ (rA0 & 3)) * 8;
    const ushort_t* b1p = Bt + (size_t)(nb + rA1) * ldb + (dr_c ^ (rA1 & 3)) * 8;
    ushort_t* asb0 = &as[(w) * 512];        ushort_t* asb1 = &as[(4 + w) * 512];
    ushort_t* bsb0 = &bs[(w) * 512];        ushort_t* bsb1 = &bs[(4 + w) * 512];

    f32x4 acc[4][4];
#pragma unroll
    for (int i = 0; i < 4; i++)
#pragma unroll
        for (int j = 0; j < 4; j++) acc[i][j] = (f32x4)0.f;

    const int chunk = quad ^ (l15 & 3);   // swizzled frag chunk

    for (int kb = 0; kb < K; kb += 32) {
        __syncthreads();                   // prev iter's frag reads done
        gld16(a0p + kb, asb0);
        gld16(a1p + kb, asb1);
        gld16(b0p + kb, bsb0);
        gld16(b1p + kb, bsb1);
        __syncthreads();                   // compiler drains vmcnt before barrier

        bf16x8 af[4], bf[4];
#pragma unroll
        for (int mt = 0; mt < 4; mt++)
            af[mt] = *(const bf16x8*)&as[(wm + mt * 16 + l15) * 32 + chunk * 8];
#pragma unroll
        for (int nt = 0; nt < 4; nt++)
            bf[nt] = *(const bf16x8*)&bs[(wn + nt * 16 + l15) * 32 + chunk * 8];
#pragma unroll
        for (int mt = 0; mt < 4; mt++)
#pragma unroll
            for (int nt = 0; nt < 4; nt++)
                acc[mt][nt] = __builtin_amdgcn_mfma_f32_16x16x32_bf16(
                    af[mt], bf[nt], acc[mt][nt], 0, 0, 0);
    }

#pragma unroll
    for (int mt = 0; mt < 4; mt++)
#pragma unroll
        for (int nt = 0; nt < 4; nt++) {
            int colg = nb + wn + nt * 16 + l15;
#pragma unroll
            for (int r = 0; r < 4; r++) {
                int row = mb + wm + mt * 16 + quad * 4 + r;
                float v = acc[mt][nt][r];
                if (out_f32)            ((float*)C1)[(size_t)row * ld1 + colg] = v;
                else if (colg < split)  ((ushort_t*)C1)[(size_t)row * ld1 + colg] = f2bf(v);
                else                    ((ushort_t*)C2)[(size_t)row * ld2 + colg - split] = f2bf(v);
            }
        }
}

// ---------------------------------------------------------------------------
// RoPE in-place on Q [SEQ,QD] and KV [SEQ,KVL] bf16 buffers in ONE launch
// (head-slot hs: 0..15 -> q heads, 16..19 -> kv heads). Precise sincosf.
// ---------------------------------------------------------------------------
__global__ __launch_bounds__(256) void rope_both(
    ushort_t* __restrict__ qb, ushort_t* __restrict__ kvb,
    const int* __restrict__ pos_ids)
{
    int idx  = blockIdx.x * 256 + threadIdx.x;
    int i    = idx & 63;
    int rem  = idx >> 6;
    int hs   = rem % (NHEADS + NKVH);
    int s    = rem / (NHEADS + NKVH);
    if (s >= SEQ) return;

    float pos = (float)pos_ids[s];
    float ang = pos * __expf(-(float)i * 0.14391156831212787f);
    float c, sn;
    sincosf(ang, &sn, &c);

    ushort_t* p = (hs < NHEADS)
        ? qb  + (size_t)s * QD  + hs * HDIM
        : kvb + (size_t)s * KVL + (hs - NHEADS) * HDIM;
    float x0 = bf2f(p[i]);
    float x1 = bf2f(p[i + 64]);
    p[i]      = f2bf(x0 * c - x1 * sn);
    p[i + 64] = f2bf(x1 * c + x0 * sn);
}

// ---------------------------------------------------------------------------
// Flash attention v12 (R17 == R16 resubmit; R16 bench was an infra failure,
// audit found no defect): split-K (R13 slot map) + single-barrier LDS
// double-buffer + gld16-direct K staging.
//  - K tiles: unpadded [64][128] x2 bufs, staged by global_load_lds with
//    chunk XOR swizzle (phys = logical ^ (row&7)); rows stride 256B == bank-
//    aligned, the &7 XOR spreads 16 lanes over 8 chunk slots -> 2-way = free
//    (m136). Source global addr carries the inverse swizzle (rule #21).
//  - V: reg-staged transpose into padded vt[2][128][72] (write-late, T14).
//  - ONE barrier per K-tile: barrier at iter end protects buf[cur^1] reuse;
//    gld16(kt+1)+V-loads issue before compute (latency hides under compute),
//    V ds_writes after compute; compiler's pre-barrier drain orders vmcnt.
//  LDS 70144B -> 2 blocks/CU (R14 measured 34.5% occupancy at this size).
//  Slot map: s<8 tiles 15-s in-place; s in 8..63 chunks of tiles>=16 ->
//  partials; s>=64 tiles 7..0 in-place. exp2 softmax, defer-max, cvt_pk,
//  ds_bpermute P-transpose, setprio on MFMA clusters.
// ---------------------------------------------------------------------------
__global__ __launch_bounds__(512, 4) void flash_mfma(
    const ushort_t* Q, const ushort_t* __restrict__ KV,
    const int* __restrict__ amask, ushort_t* O,
    ushort_t* __restrict__ Opart, float2* __restrict__ ML)
{
    __shared__ ushort_t ks[2][64 * 128];   // 32 KB: K dbuf, swizzled chunks
    __shared__ ushort_t vt[2][128 * 72];   // 36 KB: V^T dbuf, padded rows
    __shared__ float    bias[2][64];       // 0.5 KB

    const int t = threadIdx.x, w = t >> 6, lane = t & 63;
    const int quad = lane >> 4, l15 = lane & 15;
    const int h = blockIdx.x, kvh = h >> 2;
    const int s = blockIdx.y;                        // slot 0..71
    const int kcol = kvh * HDIM, vcol = KVD + kvh * HDIM;
    const float scale2 = 0.08838834764831845f * 1.44269504088896340f; // /sqrt(128)*log2e

    // slot -> (tile, chunk range, partial id)
    int tile, ktb, kte, pid;
    bool multi;
    if (s < 8)       { tile = 15 - s;        ktb = 0; kte = 2 * tile + 2; multi = false; pid = 0; }
    else if (s < 64) {
        int cs = s - 8;                               // 0..55
        int c;
        if (cs < 24) { tile = 16 + cs / 3; c = cs - (tile - 16) * 3; }
        else         { int d = cs - 24; tile = 24 + (d >> 2); c = d & 3; }
        int nkt = 2 * tile + 2;
        ktb = c * 16; kte = (ktb + 16 < nkt) ? ktb + 16 : nkt;
        multi = true; pid = h * NPART + cs;
    }
    else             { tile = 7 - (s - 64);  ktb = 0; kte = 2 * tile + 2; multi = false; pid = 0; }

    const int q0  = tile * 128;
    const int q0w = q0 + w * 16;

    // K gld16 map: 512 thr, 2 rounds; round r: row R = r*32 + (w*4+quad),
    // phys chunk l15, logical chunk = l15 ^ (R&7) (R&7 same both rounds).
    const int kRow = w * 4 + quad;                   // 0..31
    const int klc  = l15 ^ (kRow & 7);               // logical chunk
    // V staging map (reg transpose): keys 2vkp,2vkp+1, dims vdg*8..+8
    const int vkp  = t & 31,  vdg = t >> 5;

    // bpermute indices for P transpose: quad' = 2*(quad&1) + (t4>>1)
    int bpi[4];
#pragma unroll
    for (int t4 = 0; t4 < 4; t4++)
        bpi[t4] = ((2 * (quad & 1) + (t4 >> 1)) * 16 + l15) * 4;
    const bool hi_half = (quad >> 1) != 0;           // selects mt' = 2kc+1

    // physical chunk byte-offsets for QK^T frag reads: row&7 == l15&7
    int pco[4];
#pragma unroll
    for (int c = 0; c < 4; c++)
        pco[c] = ((4 * c + quad) ^ (l15 & 7)) * 8;

    // Q B-frags: qf[c] = Q[q0w + l15][c*32 + quad*8 ..+8]
    bf16x8 qf[4];
    {
        const ushort_t* qp = Q + (size_t)(q0w + l15) * QD + h * HDIM;
#pragma unroll
        for (int c = 0; c < 4; c++)
            qf[c] = *(const bf16x8*)(qp + c * 32 + quad * 8);
    }

    f32x4 accO[8];
#pragma unroll
    for (int j = 0; j < 8; j++) accO[j] = (f32x4)0.f;
    float m_s = -1e30f, l_s = 0.f;

    uint4 va, vb;
    float bst = 0.f;
    auto stage_k = [&](int kt, int b) {              // async K -> LDS (direct)
        const ushort_t* g0 = KV + (size_t)(kt * 64 + kRow) * KVL + kcol + klc * 8;
        gld16(g0, &ks[b][w * 512]);
        gld16(g0 + (size_t)32 * KVL, &ks[b][4096 + w * 512]);
    };
    auto vload = [&](int kt) {                       // V global -> regs
        const ushort_t* vp = KV + (size_t)(kt * 64 + 2 * vkp) * KVL + vcol + vdg * 8;
        va = *(const uint4_a*)vp;
        vb = *(const uint4_a*)(vp + KVL);
        bst = (t < 64) ? (amask[kt * 64 + t] ? 0.f : -1e30f) : 0.f;
    };
    auto vstore = [&](int b) {                       // regs -> vt[b] (transposed)
        unsigned aw[4] = {va.x, va.y, va.z, va.w};
        unsigned bw[4] = {vb.x, vb.y, vb.z, vb.w};
#pragma unroll
        for (int i = 0; i < 4; i++) {
            *(uint_a*)&vt[b][(vdg * 8 + 2 * i) * 72 + 2 * vkp] =
                (aw[i] & 0xFFFFu) | (bw[i] << 16);
            *(uint_a*)&vt[b][(vdg * 8 + 2 * i + 1) * 72 + 2 * vkp] =
                (aw[i] >> 16) | (bw[i] & 0xFFFF0000u);
        }
        if (t < 64) bias[b][t] = bst;
    };

    // prologue: stage tile ktb into buffer 0
    stage_k(ktb, 0);
    vload(ktb);
    vstore(0);
    __syncthreads();   // drains gld16 + ds_writes (compiler vmcnt/lgkmcnt)

    for (int kt = ktb; kt < kte; kt++) {
        const int cur = (kt - ktb) & 1;
        const int k0 = kt * 64;
        const bool more = (kt + 1 < kte);
        if (more) {                       // issue next-tile loads early (T14)
            stage_k(kt + 1, cur ^ 1);
            vload(kt + 1);
        }

        if (k0 <= q0w + 15) {             // tile not fully masked for this wave
            // ---- S^T = K Q^T ----
            f32x4 sx[4];
#pragma unroll
            for (int mt = 0; mt < 4; mt++) sx[mt] = (f32x4)0.f;
            __builtin_amdgcn_s_setprio(1);
#pragma unroll
            for (int c = 0; c < 4; c++)
#pragma unroll
                for (int mt = 0; mt < 4; mt++) {
                    bf16x8 kf = *(const bf16x8*)&ks[cur][(mt * 16 + l15) * 128 + pco[c]];
                    sx[mt] = __builtin_amdgcn_mfma_f32_16x16x32_bf16(kf, qf[c], sx[mt], 0, 0, 0);
                }
            __builtin_amdgcn_s_setprio(0);

            // ---- masked online softmax (exp2 domain); q-row = l15 ----
            const int qg = q0w + l15;
            const bool full = (k0 + 63 <= q0w);
            float p[4][4];
            float mx = -1e30f;
#pragma unroll
            for (int mt = 0; mt < 4; mt++) {
                float4 b4 = *(const float4_a*)&bias[cur][mt * 16 + quad * 4];
                float br[4] = {b4.x, b4.y, b4.z, b4.w};
#pragma unroll
                for (int r = 0; r < 4; r++) {
                    float v = fmaf(sx[mt][r], scale2, br[r]);
                    if (!full) {
                        int kg = k0 + mt * 16 + quad * 4 + r;
                        v = (kg > qg) ? -1e30f : v;
                    }
                    p[mt][r] = v;
                    mx = fmaxf(mx, v);
                }
            }
            mx = fmaxf(mx, __shfl_xor(mx, 16));
            mx = fmaxf(mx, __shfl_xor(mx, 32));
            // defer-max (T13): keep old max unless it grew by >8
            const bool renorm = !__all(mx <= m_s + 8.f);
            const float mnew = renorm ? fmaxf(m_s, mx) : m_s;
            float sum = 0.f;
            unsigned wlo[4], whi[4];
#pragma unroll
            for (int mt = 0; mt < 4; mt++) {
                float p0 = exp2f(p[mt][0] - mnew);
                float p1 = exp2f(p[mt][1] - mnew);
                float p2 = exp2f(p[mt][2] - mnew);
                float p3 = exp2f(p[mt][3] - mnew);
                sum += (p0 + p1) + (p2 + p3);
                wlo[mt] = cvt_pk(p0, p1);
                whi[mt] = cvt_pk(p2, p3);
            }
            sum += __shfl_xor(sum, 16);
            sum += __shfl_xor(sum, 32);

            if (renorm) {
                float alpha = exp2f(m_s - mnew);
                l_s *= alpha;
                float a0 = __shfl(alpha, quad * 4 + 0);
                float a1 = __shfl(alpha, quad * 4 + 1);
                float a2 = __shfl(alpha, quad * 4 + 2);
                float a3 = __shfl(alpha, quad * 4 + 3);
#pragma unroll
                for (int j = 0; j < 8; j++) {
                    f32x4 a = accO[j];
                    a[0] *= a0; a[1] *= a1; a[2] *= a2; a[3] *= a3;
                    accO[j] = a;
                }
            }
            m_s = mnew;
            l_s += sum;

            // ---- P transpose C->A layout via ds_bpermute; then O += P V ----
#pragma unroll
            for (int kc = 0; kc < 2; kc++) {
                union { unsigned u[4]; bf16x8 v; } pf;
#pragma unroll
                for (int t4 = 0; t4 < 4; t4++) {
                    unsigned slo = (t4 & 1) ? whi[2 * kc]     : wlo[2 * kc];
                    unsigned shi = (t4 & 1) ? whi[2 * kc + 1] : wlo[2 * kc + 1];
                    int ra = __builtin_amdgcn_ds_bpermute(bpi[t4], (int)slo);
                    int rb = __builtin_amdgcn_ds_bpermute(bpi[t4], (int)shi);
                    pf.u[t4] = (unsigned)(hi_half ? rb : ra);
                }
                __builtin_amdgcn_s_setprio(1);
#pragma unroll
                for (int n8 = 0; n8 < 8; n8++) {
                    bf16x8 vf = *(const bf16x8*)&vt[cur][(n8 * 16 + l15) * 72 + kc * 32 + quad * 8];
                    accO[n8] = __builtin_amdgcn_mfma_f32_16x16x32_bf16(pf.v, vf, accO[n8], 0, 0, 0);
                }
                __builtin_amdgcn_s_setprio(0);
            }
        }

        if (more) vstore(cur ^ 1);        // write-late: V regs -> other buffer
        __syncthreads();                  // single barrier: buf[cur] reads done,
                                          // gld16/ds_writes drained for next iter
    }

    if (!multi) {
        // ---- epilogue: normalize rows, store bf16 in-place over Q region ----
        float linv = 1.0f / l_s;
#pragma unroll
        for (int r = 0; r < 4; r++) {
            float lr = __shfl(linv, quad * 4 + r);
            int row = q0w + quad * 4 + r;
            ushort_t* op = O + (size_t)row * QD + h * HDIM;
#pragma unroll
            for (int n8 = 0; n8 < 8; n8++)
                op[n8 * 16 + l15] = f2bf(accO[n8][r] * lr);
        }
    } else {
        // ---- partial epilogue: unnormalized accO (bf16) + per-row (m,l) ----
        ushort_t* op = Opart + (size_t)pid * (128 * 128);
#pragma unroll
        for (int r = 0; r < 4; r++) {
            int row = w * 16 + quad * 4 + r;
#pragma unroll
            for (int n8 = 0; n8 < 8; n8++)
                op[row * 128 + n8 * 16 + l15] = f2bf(accO[n8][r]);
        }
        if (quad == 0)
            ML[pid * 128 + w * 16 + l15] = make_float2(m_s, l_s);
    }
}

// ---------------------------------------------------------------------------
// Merge split-K partials for tiles t=16..31 (coalesced): per-row weights
// wc[c][row] = 2^(m_c - M)/L precomputed in LDS; 8 lanes cover one row's
// 128B contiguous span (read AND write dense). 256 blocks (h, t), 256 thr.
// ---------------------------------------------------------------------------
__global__ __launch_bounds__(256) void combine_partials(
    const ushort_t* __restrict__ P, const float2* __restrict__ ML,
    ushort_t* __restrict__ O)
{
    __shared__ float wc[4][128];
    const int h = blockIdx.x >> 4, tt = blockIdx.x & 15, tile = 16 + tt;
    const int nc = (tile < 24) ? 3 : 4;
    const int pid0 = h * NPART + ((tile < 24) ? tt * 3 : 24 + (tile - 24) * 4);
    const int tid = threadIdx.x;

    if (tid < 128) {
        const int row = tid;
        float m_[4], l_[4];
        float M = -1e30f;
#pragma unroll
        for (int c = 0; c < 4; c++) {
            if (c < nc) {
                float2 v = *(const float2_a*)&ML[(pid0 + c) * 128 + row];
                m_[c] = v.x; l_[c] = v.y; M = fmaxf(M, v.x);
            } else { m_[c] = -1e30f; l_[c] = 0.f; }
        }
        float L = 0.f, wgt[4];
#pragma unroll
        for (int c = 0; c < 4; c++) { wgt[c] = exp2f(m_[c] - M); L += wgt[c] * l_[c]; }
        const float inv = 1.0f / L;
#pragma unroll
        for (int c = 0; c < 4; c++) wc[c][row] = (c < nc) ? wgt[c] * inv : 0.f;
    }
    __syncthreads();

#pragma unroll
    for (int p = 0; p < 4; p++) {
        const int idx = p * 256 + tid;
        const int row = idx >> 3, seg = idx & 7;     // 16 cols per seg
        const size_t pb = (size_t)row * 128 + seg * 16;
        float acc[16];
#pragma unroll
        for (int j = 0; j < 16; j++) acc[j] = 0.f;
#pragma unroll
        for (int c = 0; c < 4; c++) {
            if (c < nc) {
                const ushort_t* pp = P + (size_t)(pid0 + c) * (128 * 128) + pb;
                uint4 v0 = *(const uint4_a*)pp;
                uint4 v1 = *(const uint4_a*)(pp + 8);
                const float wv_ = wc[c][row];
                unsigned u[8] = {v0.x, v0.y, v0.z, v0.w, v1.x, v1.y, v1.z, v1.w};
#pragma unroll
                for (int j = 0; j < 8; j++) {
                    acc[2 * j]     += wv_ * bf2f((ushort_t)(u[j] & 0xFFFFu));
                    acc[2 * j + 1] += wv_ * bf2f((ushort_t)(u[j] >> 16));
                }
            }
        }
        ushort_t* op = O + (size_t)(tile * 128 + row) * QD + h * HDIM + seg * 16;
        uint4 o0, o1;
        o0.x = pack2(acc[0],  acc[1]);  o0.y = pack2(acc[2],  acc[3]);
        o0.z = pack2(acc[4],  acc[5]);  o0.w = pack2(acc[6],  acc[7]);
        o1.x = pack2(acc[8],  acc[9]);  o1.y = pack2(acc[10], acc[11]);
        o1.z = pack2(acc[12], acc[13]); o1.w = pack2(acc[14], acc[15]);
        *(uint4_a*)op       = o0;
        *(uint4_a*)(op + 8) = o1;
    }
}

// ---------------------------------------------------------------------------
// Memory plan: ws = qbuf/att 16MB | kvbuf (k|v interleaved) 8MB | (woT 8MB
// overwrites kvbuf after flash+combine). d_out scratch: wqkvT 12MB | xb 16MB
// until QKV GEMM; then flash partials: Opart 28MB | ML 0.9MB; O-GEMM output
// overwrites after combine.
// ---------------------------------------------------------------------------
extern "C" void kernel_launch(void* const* d_in, const int* in_sizes, int n_in,
                              void* d_out, int out_size, void* d_ws, size_t ws_size,
                              hipStream_t stream)
{
    const float* x     = (const float*)d_in[0];
    const int*   amask = (const int*)d_in[1];
    const int*   pos   = (const int*)d_in[2];
    const float* wq    = (const float*)d_in[3];
    const float* wk    = (const float*)d_in[4];
    const float* wv    = (const float*)d_in[5];
    const float* wo    = (const float*)d_in[6];
    float* out = (float*)d_out;

    ushort_t* wqkvT = (ushort_t*)d_out;                    // [3072][2048] bf16
    ushort_t* xb    = wqkvT + (size_t)3072 * HID;          // [4096][2048] bf16

    ushort_t* qbuf  = (ushort_t*)d_ws;                     // [4096][2048]
    ushort_t* kvbuf = qbuf + (size_t)SEQ * QD;             // [4096][1024] k|v
    ushort_t* woT   = kvbuf;                               // [2048][2048] after flash

    // split-K partials live in d_out during attention
    ushort_t* opart = (ushort_t*)d_out;                    // 896 x 128 x 128 bf16 = 28MB
    float2*   mlbuf = (float2*)((char*)d_out + (size_t)16 * NPART * 128 * 128 * 2);

    cast_f32_bf16<<<SEQ * HID / 8 / 256, 256, 0, stream>>>(x, xb, SEQ * HID);
    // fused wq|wk|wv transpose (one launch)
    transpose_cast_qkv<<<dim3(HID / 32, 3072 / 32), 256, 0, stream>>>(wq, wk, wv, wqkvT);

    // fused QKV projection: cols [0,2048) -> qbuf, [2048,3072) -> kvbuf
    gemm_mfma<<<dim3(3072 / 128, SEQ / 128), 256, 0, stream>>>(
        xb, HID, wqkvT, HID, qbuf, QD, kvbuf, KVL, QD, 3072, HID, 0);

    // fused RoPE on Q and KV in one launch
    rope_both<<<SEQ * (NHEADS + NKVH) * 64 / 256, 256, 0, stream>>>(qbuf, kvbuf, pos);

    // split-K flash: 16 heads x 72 slots = 1152 blocks, 2 resident/CU + backfill
    flash_mfma<<<dim3(NHEADS, 72), 512, 0, stream>>>(
        qbuf, kvbuf, amask, qbuf, opart, mlbuf);
    combine_partials<<<dim3(256), 256, 0, stream>>>(opart, mlbuf, qbuf);

    transpose_cast<<<dim3(QD / 32, HID / 32), 256, 0, stream>>>(wo, woT, QD, HID);
    gemm_mfma<<<dim3(HID / 128, SEQ / 128), 256, 0, stream>>>(
        qbuf, QD, woT, QD, out, HID, out, HID, HID, HID, QD, 1);
}